// Round 15
// baseline (239.539 us; speedup 1.0000x reference)
//
#include <hip/hip_runtime.h>
#include <hip/hip_bf16.h>

// Problem constants (ContextualAttention):
//  B=2, C=128, H=W=96, rate=2 -> h=w=48, L=2304, kernel=4, KSIZE=3, SCALE=10
#define Cc   128
#define Hh   96
#define hs   48
#define Ls   2304      // 48*48
#define CK   2048      // C*16
#define KG   384       // Gram split-K: [h|lo|h] / [h|h|lo]

typedef __attribute__((ext_vector_type(8))) short short8;
typedef __attribute__((ext_vector_type(4))) float f32x4;

__device__ __forceinline__ unsigned short f2bf(float x) {
    unsigned int u = __float_as_uint(x);
    unsigned int r = (u + 0x7fff + ((u >> 16) & 1)) >> 16;   // RNE
    return (unsigned short)r;
}
__device__ __forceinline__ float bf2f(unsigned short h) {
    return __uint_as_float((unsigned)h << 16);
}

// unaligned-tolerant 16B vector load (addr is 4B-aligned)
__device__ __forceinline__ f32x4 ld4u(const float* p) {
    f32x4 v; __builtin_memcpy(&v, p, 16); return v;
}

#define GLOAD_LDS16(g, l) \
    __builtin_amdgcn_global_load_lds((__attribute__((address_space(1))) const void*)(g), \
                                     (__attribute__((address_space(3))) void*)(l), 16, 0, 0)

// ---------------- small kernels ----------------

// fused subsample + transpose + bf16 hi/lo split: x2 -> P,Q [l][384]
__global__ __launch_bounds__(256) void transposePQ_k(const float* __restrict__ x2,
                                                     unsigned short* __restrict__ P,
                                                     unsigned short* __restrict__ Q,
                                                     long long sPQ, int z0) {
    const int z = z0 + blockIdx.z;
    const float* x2b = x2 + (size_t)z * Cc * Hh * Hh;
    unsigned short* Pb = P + (size_t)blockIdx.z * sPQ;
    unsigned short* Qb = Q + (size_t)blockIdx.z * sPQ;
    __shared__ float tile[64][65];
    const int c0 = blockIdx.x * 64;      // 0 or 64
    const int l0 = blockIdx.y * 64;      // 36 tiles
    const int t = threadIdx.x;
    const int lt = t & 63, cg = t >> 6;  // cg 0..3
    const int l = l0 + lt;
    const int iy = l / hs, jx = l % hs;
    const int srcoff = iy * (2 * Hh) + 2 * jx;
#pragma unroll
    for (int cc = 0; cc < 16; ++cc) {
        int c = cg * 16 + cc;
        tile[lt][c] = x2b[(size_t)(c0 + c) * (Hh * Hh) + srcoff];
    }
    __syncthreads();
    const int lr = t >> 2, seg = t & 3;
    const int lw = l0 + lr;
    short8 hv0, hv1, lv0, lv1;
#pragma unroll
    for (int k = 0; k < 8; ++k) {
        float x = tile[lr][seg * 16 + k];
        unsigned short h = f2bf(x);
        float hf = __uint_as_float((unsigned)h << 16);
        unsigned short lo = f2bf(x - hf);
        hv0[k] = (short)h; lv0[k] = (short)lo;
    }
#pragma unroll
    for (int k = 0; k < 8; ++k) {
        float x = tile[lr][seg * 16 + 8 + k];
        unsigned short h = f2bf(x);
        float hf = __uint_as_float((unsigned)h << 16);
        unsigned short lo = f2bf(x - hf);
        hv1[k] = (short)h; lv1[k] = (short)lo;
    }
    size_t rowp = (size_t)lw * KG;
    int coff = c0 + seg * 16;
    *(short8*)&Pb[rowp + coff] = hv0;        *(short8*)&Pb[rowp + coff + 8] = hv1;
    *(short8*)&Pb[rowp + 128 + coff] = lv0;  *(short8*)&Pb[rowp + 128 + coff + 8] = lv1;
    *(short8*)&Pb[rowp + 256 + coff] = hv0;  *(short8*)&Pb[rowp + 256 + coff + 8] = hv1;
    *(short8*)&Qb[rowp + coff] = hv0;        *(short8*)&Qb[rowp + coff + 8] = hv1;
    *(short8*)&Qb[rowp + 128 + coff] = hv0;  *(short8*)&Qb[rowp + 128 + coff + 8] = hv1;
    *(short8*)&Qb[rowp + 256 + coff] = lv0;  *(short8*)&Qb[rowp + 256 + coff + 8] = lv1;
}

__global__ __launch_bounds__(256) void mm_k(const float* __restrict__ mask, float* __restrict__ MM) {
    int z = blockIdx.y;
    const float* mb = mask + (size_t)z * hs * hs;
    float* MMb = MM + (size_t)z * Ls;
    int l = blockIdx.x * 256 + threadIdx.x;
    if (l >= Ls) return;
    int ly = l / hs, lx = l % hs;
    float s = 0.f;
    for (int dy = -1; dy <= 1; ++dy)
        for (int dx = -1; dx <= 1; ++dx) {
            int yy = ly + dy, xx = lx + dx;
            if ((unsigned)yy < (unsigned)hs && (unsigned)xx < (unsigned)hs) s += mb[yy * hs + xx];
        }
    float m = s * (1.0f / 9.0f);
    MMb[l] = (m == 0.0f) ? 1.0f : 0.0f;
}

// fused taps + rnorm, vectorized: each thread computes 4 consecutive j for one i.
// G must have >=2KB guard bands on both sides.
__global__ __launch_bounds__(256) void taps9rn_k(const float* __restrict__ G, float* __restrict__ S,
                                                 float* __restrict__ RN, long long zsG, long long zsS, int z0) {
    const float* Gb = G + (size_t)blockIdx.z * zsG;
    float* Sb = S + (size_t)blockIdx.z * zsS;
    float* RNb = RN + (size_t)(z0 + blockIdx.z) * Ls;
    int g = blockIdx.x * 256 + threadIdx.x;      // < 2304*576
    int i = g / 576;
    int jb = (g - i * 576) * 4;
    int iy = i / hs, ix = i % hs;
    int jy = jb / hs, jx0 = jb % hs;
    f32x4 acc = {};
#pragma unroll
    for (int dy = -1; dy <= 1; ++dy) {
        int vy = ((unsigned)(iy + dy) < (unsigned)hs) && ((unsigned)(jy + dy) < (unsigned)hs);
#pragma unroll
        for (int dx = -1; dx <= 1; ++dx) {
            int vi = vy && ((unsigned)(ix + dx) < (unsigned)hs);
            int o = hs * dy + dx;
            int row = vi ? (i + o) : i;
            f32x4 v = ld4u(&Gb[(size_t)row * Ls + jb + o]);
            f32x4 m;
#pragma unroll
            for (int ln = 0; ln < 4; ++ln)
                m[ln] = (vi && ((unsigned)(jx0 + ln + dx) < (unsigned)hs)) ? 1.f : 0.f;
            acc += v * m;
        }
    }
    __builtin_memcpy(&Sb[(size_t)i * Ls + jb], &acc, 16);
    int dd = i - jb;
    if ((unsigned)dd < 4u) RNb[i] = 1.0f / fmaxf(sqrtf(acc[dd]), 1e-4f);
}

// fused fuse2(fuse1) with transposed output, vectorized 4j x 4i per thread.
// S must have >=2KB guard bands on both sides.
__global__ __launch_bounds__(256) void fuse12T_k(const float* __restrict__ S, const float* __restrict__ RN,
                                                 float* __restrict__ ZT, long long zsS, long long zsZT, int z0) {
    const float* Sb = S + (size_t)blockIdx.z * zsS;
    float* ZTb = ZT + (size_t)blockIdx.z * zsZT;
    const float* RNb = RN + (size_t)(z0 + blockIdx.z) * Ls;
    __shared__ float tile[64][65];
    const int i0 = blockIdx.y * 64, j0 = blockIdx.x * 64;
    const int t = threadIdx.x;
    const int jg = t & 15, tit = t >> 4;
    const int jb = j0 + jg * 4;
    const int jy0 = jb / hs, jx0 = jb % hs;

    int ccb[9]; f32x4 m4[9];
#pragma unroll
    for (int d2 = -1; d2 <= 1; ++d2) {
        int cl[4], vb[4];
#pragma unroll
        for (int ln = 0; ln < 4; ++ln) {
            int j2 = (jx0 + ln) * hs + jy0 + d2;
            int vv = ((unsigned)j2 < (unsigned)Ls) ? 1 : 0;
            int c = vv ? ((j2 % hs) * hs + j2 / hs) : 0;
            cl[ln] = c; vb[ln] = vv;
        }
        int base = 0;
#pragma unroll
        for (int ln = 0; ln < 4; ++ln) if (vb[ln]) base = cl[ln] - ln;
#pragma unroll
        for (int d1 = -1; d1 <= 1; ++d1) {
            int idx = (d2 + 1) * 3 + (d1 + 1);
            ccb[idx] = base + d1;
            f32x4 mm;
#pragma unroll
            for (int ln = 0; ln < 4; ++ln) {
                int cc = cl[ln] + d1;
                mm[ln] = (vb[ln] && ((unsigned)cc < (unsigned)Ls)) ? 1.f : 0.f;
            }
            m4[idx] = mm;
        }
    }

    f32x4 acc[4] = {};
#pragma unroll
    for (int kk = 0; kk < 4; ++kk) {
        const int i = i0 + tit * 4 + kk;
        const int iy = i / hs, ix = i % hs;
        const int tif = ix * hs + iy;
#pragma unroll
        for (int d2 = -1; d2 <= 1; ++d2) {
            int i2 = tif + d2;
            int vi = ((unsigned)i2 < (unsigned)Ls) ? 1 : 0;
            int r = vi ? ((i2 % hs) * hs + i2 / hs) : 1;
#pragma unroll
            for (int d1 = -1; d1 <= 1; ++d1) {
                int rr = r + d1;
                int vr = vi && ((unsigned)rr < (unsigned)Ls);
                int rrc = vr ? rr : 0;
                float w = RNb[rrc];
                w = vr ? w : 0.f;
                int idx = (d2 + 1) * 3 + (d1 + 1);
                f32x4 v = ld4u(&Sb[(size_t)rrc * Ls + ccb[idx]]);
                acc[kk] += v * m4[idx] * w;
            }
        }
    }
#pragma unroll
    for (int kk = 0; kk < 4; ++kk) {
        int ti = tit * 4 + kk;
        tile[ti][jg * 4 + 0] = acc[kk][0];
        tile[ti][jg * 4 + 1] = acc[kk][1];
        tile[ti][jg * 4 + 2] = acc[kk][2];
        tile[ti][jg * 4 + 3] = acc[kk][3];
    }
    __syncthreads();
    const int r2 = t >> 2, cs = (t & 3) * 16;
    float vbuf[16];
#pragma unroll
    for (int k = 0; k < 16; ++k) vbuf[k] = tile[cs + k][r2];
    float* dst = &ZTb[(size_t)(j0 + r2) * Ls + i0 + cs];
#pragma unroll
    for (int k = 0; k < 4; ++k)
        *(float4*)&dst[k * 4] = *(float4*)&vbuf[k * 4];
}

// row softmax over ZT[p][l] (coalesced), writes bf16 AT[p][l]
__global__ __launch_bounds__(256) void softmax_row_k(const float* __restrict__ ZT, const float* __restrict__ MM,
                                                     unsigned short* __restrict__ AT, long long zsZT, int z0) {
    const int z = z0 + blockIdx.z;
    const float* ZTb = ZT + (size_t)blockIdx.z * zsZT;
    const float* MMb = MM + (size_t)z * Ls;
    unsigned short* ATb = AT + (size_t)z * Ls * Ls;
    const int w = threadIdx.x >> 6, lane = threadIdx.x & 63;
    const int p = blockIdx.x * 4 + w;
    const float* row = ZTb + (size_t)p * Ls;
    float v[36];
    float mx = -3.4e38f;
#pragma unroll
    for (int k = 0; k < 9; ++k) {
        const float4 zv = *(const float4*)&row[k * 256 + lane * 4];
        const float4 m = *(const float4*)&MMb[k * 256 + lane * 4];
        v[4 * k + 0] = zv.x * m.x * 10.f;
        v[4 * k + 1] = zv.y * m.y * 10.f;
        v[4 * k + 2] = zv.z * m.z * 10.f;
        v[4 * k + 3] = zv.w * m.w * 10.f;
        mx = fmaxf(mx, fmaxf(fmaxf(v[4 * k], v[4 * k + 1]), fmaxf(v[4 * k + 2], v[4 * k + 3])));
    }
#pragma unroll
    for (int off = 32; off; off >>= 1) mx = fmaxf(mx, __shfl_xor(mx, off));
    float sum = 0.f;
#pragma unroll
    for (int kk = 0; kk < 36; ++kk) { v[kk] = expf(v[kk] - mx); sum += v[kk]; }
#pragma unroll
    for (int off = 32; off; off >>= 1) sum += __shfl_xor(sum, off);
    const float rs = 1.0f / sum;
#pragma unroll
    for (int k = 0; k < 9; ++k) {
        const float4 m = *(const float4*)&MMb[k * 256 + lane * 4];
        ushort4 o;
        o.x = f2bf(fmaxf(v[4 * k + 0] * rs * m.x, 1e-8f));
        o.y = f2bf(fmaxf(v[4 * k + 1] * rs * m.y, 1e-8f));
        o.z = f2bf(fmaxf(v[4 * k + 2] * rs * m.z, 1e-8f));
        o.w = f2bf(fmaxf(v[4 * k + 3] * rs * m.w, 1e-8f));
        *(ushort4*)&ATb[(size_t)p * Ls + k * 256 + lane * 4] = o;
    }
}

// raw_w^T gather (bf16, N-major K-contiguous), z-batched
__global__ __launch_bounds__(256) void gather_rwT_k(const float* __restrict__ x1, unsigned short* __restrict__ RWT) {
    const int z = blockIdx.z;
    const float* x1b = x1 + (size_t)z * Cc * Hh * Hh;
    unsigned short* R = RWT + (size_t)z * CK * Ls;
    int l = blockIdx.x * 256 + threadIdx.x;   // < 2304
    int ck = blockIdx.y;                      // < 2048
    int c = ck >> 4, a = (ck >> 2) & 3, b2 = ck & 3;
    int ly = l / hs, lx = l % hs;
    int u = 2 * ly + a - 1, vv = 2 * lx + b2 - 1;
    float val = ((unsigned)u < (unsigned)Hh && (unsigned)vv < (unsigned)Hh) ? x1b[c * (Hh * Hh) + u * Hh + vv] : 0.0f;
    R[(size_t)ck * Ls + l] = f2bf(val);
}

// LDS-gather scatter summing two split-K partial T buffers: block = (channel, yhalf, z); T is bf16.
__global__ __launch_bounds__(256) void scatter3_k(const unsigned short* __restrict__ T, float* __restrict__ out) {
    const int z = blockIdx.z;
    const int c = blockIdx.x;
    const int yh = blockIdx.y;                 // 0 or 1
    const unsigned short* Tb0 = T + (size_t)(2 * z + 0) * Ls * CK + (size_t)c * 16;
    const unsigned short* Tb1 = T + (size_t)(2 * z + 1) * Ls * CK + (size_t)c * 16;
    float* outb = out + (size_t)z * Cc * Hh * Hh + (size_t)c * Hh * Hh;
    const int i0 = (yh == 0) ? 0 : 23;          // i range [i0, i0+25)
    __shared__ unsigned short Tl[1200 * 16];    // 25*48 rows x 16 bf16 = 38.4 KB
    const int t = threadIdx.x;
#pragma unroll
    for (int rep = 0; rep < 5; ++rep) {
        int p = rep * 256 + t;
        if (p < 1200) {
            short8 h0a, h0b, h1a, h1b;
            size_t off = (size_t)(i0 * hs + p) * CK;
            __builtin_memcpy(&h0a, &Tb0[off], 16);
            __builtin_memcpy(&h0b, &Tb0[off + 8], 16);
            __builtin_memcpy(&h1a, &Tb1[off], 16);
            __builtin_memcpy(&h1b, &Tb1[off + 8], 16);
            short8 s0, s1;
#pragma unroll
            for (int e = 0; e < 8; ++e) {
                s0[e] = (short)f2bf(bf2f((unsigned short)h0a[e]) + bf2f((unsigned short)h1a[e]));
                s1[e] = (short)f2bf(bf2f((unsigned short)h0b[e]) + bf2f((unsigned short)h1b[e]));
            }
            *(short8*)&Tl[p * 16] = s0;
            *(short8*)&Tl[p * 16 + 8] = s1;
        }
    }
    __syncthreads();
#pragma unroll
    for (int rep = 0; rep < 5; ++rep) {
        int idx4 = rep * 256 + t;              // < 1152 (48 rows x 24 float4)
        if (idx4 >= 1152) break;
        int Y = yh * 48 + idx4 / 24;
        int X0 = (idx4 % 24) * 4;
        float o4[4];
#pragma unroll
        for (int xi = 0; xi < 4; ++xi) {
            int X = X0 + xi;
            int a0 = (Y + 1) & 1, b0 = (X + 1) & 1;
            float s = 0.f;
#pragma unroll
            for (int ai = 0; ai < 2; ++ai) {
                int a = a0 + 2 * ai;
                int i = (Y + 1 - a) >> 1;
                if ((unsigned)i >= (unsigned)hs) continue;
#pragma unroll
                for (int bi = 0; bi < 2; ++bi) {
                    int b2 = b0 + 2 * bi;
                    int jj = (X + 1 - b2) >> 1;
                    if ((unsigned)jj >= (unsigned)hs) continue;
                    s += bf2f(Tl[((i - i0) * hs + jj) * 16 + a * 4 + b2]);
                }
            }
            o4[xi] = 0.25f * s;
        }
        *(float4*)&outb[Y * Hh + X0] = *(float4*)&o4[0];
    }
}

// ---------------- bf16 MFMA GEMM, 2-phase double-buffered, LDS slot-swizzled ----------------
// C[M,N] = A[M,K] * Bt[N,K]^T. SUPER: 4x3 supertile remap (grid must be 16x18).
// CBF16: C written as bf16, else f32.
// SPLITK: blockIdx.z = (sample<<1)|half; each slice computes K/2 columns starting at half*K/2
// and writes its own C buffer (C + blockIdx.z*sC). K param is the row stride AND full extent.
template <int SUPER, int CBF16, int SPLITK>
__global__ __launch_bounds__(256) void mfma_gemm_k(const unsigned short* __restrict__ A,
                                                   const unsigned short* __restrict__ Bt,
                                                   void* __restrict__ Cv, int M, int N, int K,
                                                   long long sA, long long sB, long long sC) {
    int zs = blockIdx.z, half = 0;
    if (SPLITK) { half = zs & 1; zs >>= 1; }
    const int kbase = SPLITK ? half * (K >> 1) : 0;
    A  += (size_t)zs * sA + kbase;
    Bt += (size_t)zs * sB + kbase;
    float* Cf = (float*)Cv + (CBF16 ? 0 : (size_t)blockIdx.z * sC);
    unsigned short* Ch = (unsigned short*)Cv + (CBF16 ? (size_t)blockIdx.z * sC : 0);

    // bijective XCD-aware remap over (x,y)
    const int nb = gridDim.x * gridDim.y;
    const int flat = blockIdx.y * gridDim.x + blockIdx.x;
    const int q = nb >> 3, r = nb & 7;
    const int xcd = flat & 7, sidx = flat >> 3;
    const int wg = (xcd < r ? xcd * (q + 1) : r * (q + 1) + (xcd - r) * q) + sidx;
    int bm, bn;
    if (SUPER) {
        int st = wg / 12, tt = wg % 12;
        int stn = st & 3, stm = st >> 2;     // 4 x 6 supertile grid
        int tn = tt & 3, tm = tt >> 2;       // 4(n) x 3(m) within
        bn = (stn * 4 + tn) * 128;
        bm = (stm * 3 + tm) * 128;
    } else {
        bm = (wg / gridDim.x) * 128;
        bn = (wg % gridDim.x) * 128;
    }

    __shared__ __align__(16) unsigned short Asm[2][128 * 32];
    __shared__ __align__(16) unsigned short Bsm[2][128 * 32];
    const int t = threadIdx.x;
    const int lane = t & 63, w = t >> 6;
    const int wr = w >> 1, wc = w & 1;

    // staging: lane's 16B -> row rA, phys slot (lane&3); logical kslot = (lane&3)^((rA>>1)&3)
    const int rA = 32 * w + (lane >> 2);
    const int kA = (((lane & 3) ^ ((lane >> 3) & 3))) * 8;
    const unsigned short* gA0 = A + (size_t)(bm + rA) * K + kA;
    const unsigned short* gA1 = gA0 + (size_t)16 * K;   // row rA+16: same swizzle
    const unsigned short* gB0 = Bt + (size_t)(bn + rA) * K + kA;
    const unsigned short* gB1 = gB0 + (size_t)16 * K;

#define STAGE4(b, koff) do { \
        GLOAD_LDS16(gA0 + (koff), &Asm[b][(2 * w) * 512]); \
        GLOAD_LDS16(gA1 + (koff), &Asm[b][(2 * w + 1) * 512]); \
        GLOAD_LDS16(gB0 + (koff), &Bsm[b][(2 * w) * 512]); \
        GLOAD_LDS16(gB1 + (koff), &Bsm[b][(2 * w + 1) * 512]); \
    } while (0)

    const int fr = lane & 15, fq = lane >> 4;
    const int sqa = (fq ^ ((fr >> 1) & 3)) * 8;     // read-side swizzle
    f32x4 acc[4][4] = {};

    const int nt = (SPLITK ? (K >> 1) : K) >> 5;
    STAGE4(0, 0);
    __syncthreads();
    int cur = 0;
    for (int tt = 0; tt < nt; ++tt) {
        if (tt + 1 < nt) STAGE4(cur ^ 1, (tt + 1) * 32);
        short8 av[4], bv[4];
#pragma unroll
        for (int m = 0; m < 4; ++m)
            av[m] = *(const short8*)&Asm[cur][(wr * 64 + m * 16 + fr) * 32 + sqa];
#pragma unroll
        for (int n = 0; n < 4; ++n)
            bv[n] = *(const short8*)&Bsm[cur][(wc * 64 + n * 16 + fr) * 32 + sqa];
#pragma unroll
        for (int m = 0; m < 4; ++m)
#pragma unroll
            for (int n = 0; n < 4; ++n)
                acc[m][n] = __builtin_amdgcn_mfma_f32_16x16x32_bf16(av[m], bv[n], acc[m][n], 0, 0, 0);
        __syncthreads();
        cur ^= 1;
    }
#undef STAGE4

#pragma unroll
    for (int m = 0; m < 4; ++m) {
        int row0 = bm + wr * 64 + m * 16 + fq * 4;
#pragma unroll
        for (int n = 0; n < 4; ++n) {
            int col = bn + wc * 64 + n * 16 + fr;
#pragma unroll
            for (int rr = 0; rr < 4; ++rr) {
                if (CBF16)
                    Ch[(size_t)(row0 + rr) * N + col] = f2bf(acc[m][n][rr]);
                else
                    Cf[(size_t)(row0 + rr) * N + col] = acc[m][n][rr];
            }
        }
    }
}

// ---------------- launch ----------------

extern "C" void kernel_launch(void* const* d_in, const int* in_sizes, int n_in,
                              void* d_out, int out_size, void* d_ws, size_t ws_size,
                              hipStream_t stream) {
    const float* x1 = (const float*)d_in[0];
    const float* x2 = (const float*)d_in[1];
    const float* mask = (const float*)d_in[2];
    float* out = (float*)d_out;

    char* base = (char*)d_ws;
    const size_t LsLs = (size_t)Ls * Ls;
    const size_t LsCK = (size_t)Ls * CK;
    const long long sPQ = (long long)Ls * KG;

    const bool batched = ws_size >= 132175872ull;

    float* MM2 = (float*)(base);
    float* RN2 = (float*)(base + 20480);
    unsigned short *P, *Q, *ATb2, *RWT2;
    float *G, *S;
    // T2: 4 bf16 partial buffers (2 samples x 2 K-halves) = 37,748,736 B overlay at base.
    // Everything in [0, 37.7MB) (MM2/RN2/P/Q/G-prefix) is dead by deconv time; ATb2/RWT2 live above.
    unsigned short* T2 = (unsigned short*)base;
    if (batched) {
        P    = (unsigned short*)(base + 40960);
        Q    = (unsigned short*)(base + 3584000);
        G    = (float*)(base + 7127040);        // 2KB guards around
        S    = (float*)(base + 49598464);       // 2KB guards around
        ATb2 = (unsigned short*)(base + 92067840);
        RWT2 = (unsigned short*)(base + 113301504);   // end 132,175,872
    } else {
        P    = (unsigned short*)(base + 40960);
        Q    = (unsigned short*)(base + 1812480);
        G    = (float*)(base + 3586048);
        S    = (float*)(base + 24823808);
        ATb2 = (unsigned short*)(base + 46059520);
        RWT2 = (unsigned short*)(base + 67293184);    // end 86,167,552
    }

    mm_k<<<dim3(Ls / 256, 2), 256, 0, stream>>>(mask, MM2);
    gather_rwT_k<<<dim3(Ls / 256, CK, 2), 256, 0, stream>>>(x1, RWT2);

    const int tapsGrid = (Ls * 576) / 256;   // 5184

    if (batched) {
        transposePQ_k<<<dim3(2, Ls / 64, 2), 256, 0, stream>>>(x2, P, Q, sPQ, 0);
        mfma_gemm_k<0, 0, 0><<<dim3(Ls / 128, Ls / 128, 2), 256, 0, stream>>>(
            P, Q, G, Ls, Ls, KG, sPQ, sPQ, (long long)LsLs);
        taps9rn_k<<<dim3(tapsGrid, 1, 2), 256, 0, stream>>>(G, S, RN2, (long long)LsLs, (long long)LsLs, 0);
        fuse12T_k<<<dim3(Ls / 64, Ls / 64, 2), 256, 0, stream>>>(S, RN2, G, (long long)LsLs, (long long)LsLs, 0);
        softmax_row_k<<<dim3(Ls / 4, 1, 2), 256, 0, stream>>>(G, MM2, ATb2, (long long)LsLs, 0);
    } else {
        for (int z0 = 0; z0 < 2; ++z0) {
            transposePQ_k<<<dim3(2, Ls / 64, 1), 256, 0, stream>>>(x2, P, Q, 0, z0);
            mfma_gemm_k<0, 0, 0><<<dim3(Ls / 128, Ls / 128, 1), 256, 0, stream>>>(
                P, Q, G, Ls, Ls, KG, 0, 0, 0);
            taps9rn_k<<<dim3(tapsGrid, 1, 1), 256, 0, stream>>>(G, S, RN2, 0, 0, z0);
            fuse12T_k<<<dim3(Ls / 64, Ls / 64, 1), 256, 0, stream>>>(S, RN2, G, 0, 0, z0);
            softmax_row_k<<<dim3(Ls / 4, 1, 1), 256, 0, stream>>>(G, MM2, ATb2, 0, z0);
        }
    }

    // split-K batched deconv GEMM (bf16 partial C per (sample, K-half)):
    // 1152 blocks = ~4.5/CU for cross-block drain hiding (r13 mechanism).
    mfma_gemm_k<1, 1, 1><<<dim3(CK / 128, Ls / 128, 4), 256, 0, stream>>>(
        ATb2, RWT2, T2, Ls, CK, Ls,
        (long long)LsLs, (long long)LsCK, (long long)LsCK);

    scatter3_k<<<dim3(Cc, 2, 2), 256, 0, stream>>>(T2, out);

    (void)in_sizes; (void)n_in; (void)out_size; (void)ws_size;
}

// Round 16
// 221.910 us; speedup vs baseline: 1.0794x; 1.0794x over previous
//
#include <hip/hip_runtime.h>
#include <hip/hip_bf16.h>

// Problem constants (ContextualAttention):
//  B=2, C=128, H=W=96, rate=2 -> h=w=48, L=2304, kernel=4, KSIZE=3, SCALE=10
#define Cc   128
#define Hh   96
#define hs   48
#define Ls   2304      // 48*48
#define CK   2048      // C*16
#define KG   384       // Gram split-K: [h|lo|h] / [h|h|lo]

typedef __attribute__((ext_vector_type(8))) short short8;
typedef __attribute__((ext_vector_type(4))) float f32x4;

__device__ __forceinline__ unsigned short f2bf(float x) {
    unsigned int u = __float_as_uint(x);
    unsigned int r = (u + 0x7fff + ((u >> 16) & 1)) >> 16;   // RNE
    return (unsigned short)r;
}
__device__ __forceinline__ float bf2f(unsigned short h) {
    return __uint_as_float((unsigned)h << 16);
}

// unaligned-tolerant 16B vector load (addr is 4B-aligned)
__device__ __forceinline__ f32x4 ld4u(const float* p) {
    f32x4 v; __builtin_memcpy(&v, p, 16); return v;
}

#define GLOAD_LDS16(g, l) \
    __builtin_amdgcn_global_load_lds((__attribute__((address_space(1))) const void*)(g), \
                                     (__attribute__((address_space(3))) void*)(l), 16, 0, 0)

// ---------------- small kernels ----------------

// fused subsample + transpose + bf16 hi/lo split: x2 -> P,Q [l][384]
__global__ __launch_bounds__(256) void transposePQ_k(const float* __restrict__ x2,
                                                     unsigned short* __restrict__ P,
                                                     unsigned short* __restrict__ Q,
                                                     long long sPQ, int z0) {
    const int z = z0 + blockIdx.z;
    const float* x2b = x2 + (size_t)z * Cc * Hh * Hh;
    unsigned short* Pb = P + (size_t)blockIdx.z * sPQ;
    unsigned short* Qb = Q + (size_t)blockIdx.z * sPQ;
    __shared__ float tile[64][65];
    const int c0 = blockIdx.x * 64;      // 0 or 64
    const int l0 = blockIdx.y * 64;      // 36 tiles
    const int t = threadIdx.x;
    const int lt = t & 63, cg = t >> 6;  // cg 0..3
    const int l = l0 + lt;
    const int iy = l / hs, jx = l % hs;
    const int srcoff = iy * (2 * Hh) + 2 * jx;
#pragma unroll
    for (int cc = 0; cc < 16; ++cc) {
        int c = cg * 16 + cc;
        tile[lt][c] = x2b[(size_t)(c0 + c) * (Hh * Hh) + srcoff];
    }
    __syncthreads();
    const int lr = t >> 2, seg = t & 3;
    const int lw = l0 + lr;
    short8 hv0, hv1, lv0, lv1;
#pragma unroll
    for (int k = 0; k < 8; ++k) {
        float x = tile[lr][seg * 16 + k];
        unsigned short h = f2bf(x);
        float hf = __uint_as_float((unsigned)h << 16);
        unsigned short lo = f2bf(x - hf);
        hv0[k] = (short)h; lv0[k] = (short)lo;
    }
#pragma unroll
    for (int k = 0; k < 8; ++k) {
        float x = tile[lr][seg * 16 + 8 + k];
        unsigned short h = f2bf(x);
        float hf = __uint_as_float((unsigned)h << 16);
        unsigned short lo = f2bf(x - hf);
        hv1[k] = (short)h; lv1[k] = (short)lo;
    }
    size_t rowp = (size_t)lw * KG;
    int coff = c0 + seg * 16;
    *(short8*)&Pb[rowp + coff] = hv0;        *(short8*)&Pb[rowp + coff + 8] = hv1;
    *(short8*)&Pb[rowp + 128 + coff] = lv0;  *(short8*)&Pb[rowp + 128 + coff + 8] = lv1;
    *(short8*)&Pb[rowp + 256 + coff] = hv0;  *(short8*)&Pb[rowp + 256 + coff + 8] = hv1;
    *(short8*)&Qb[rowp + coff] = hv0;        *(short8*)&Qb[rowp + coff + 8] = hv1;
    *(short8*)&Qb[rowp + 128 + coff] = hv0;  *(short8*)&Qb[rowp + 128 + coff + 8] = hv1;
    *(short8*)&Qb[rowp + 256 + coff] = lv0;  *(short8*)&Qb[rowp + 256 + coff + 8] = lv1;
}

__global__ __launch_bounds__(256) void mm_k(const float* __restrict__ mask, float* __restrict__ MM) {
    int z = blockIdx.y;
    const float* mb = mask + (size_t)z * hs * hs;
    float* MMb = MM + (size_t)z * Ls;
    int l = blockIdx.x * 256 + threadIdx.x;
    if (l >= Ls) return;
    int ly = l / hs, lx = l % hs;
    float s = 0.f;
    for (int dy = -1; dy <= 1; ++dy)
        for (int dx = -1; dx <= 1; ++dx) {
            int yy = ly + dy, xx = lx + dx;
            if ((unsigned)yy < (unsigned)hs && (unsigned)xx < (unsigned)hs) s += mb[yy * hs + xx];
        }
    float m = s * (1.0f / 9.0f);
    MMb[l] = (m == 0.0f) ? 1.0f : 0.0f;
}

// fused taps + rnorm, vectorized: each thread computes 4 consecutive j for one i.
// G must have >=2KB guard bands on both sides.
__global__ __launch_bounds__(256) void taps9rn_k(const float* __restrict__ G, float* __restrict__ S,
                                                 float* __restrict__ RN, long long zsG, long long zsS, int z0) {
    const float* Gb = G + (size_t)blockIdx.z * zsG;
    float* Sb = S + (size_t)blockIdx.z * zsS;
    float* RNb = RN + (size_t)(z0 + blockIdx.z) * Ls;
    int g = blockIdx.x * 256 + threadIdx.x;      // < 2304*576
    int i = g / 576;
    int jb = (g - i * 576) * 4;
    int iy = i / hs, ix = i % hs;
    int jy = jb / hs, jx0 = jb % hs;
    f32x4 acc = {};
#pragma unroll
    for (int dy = -1; dy <= 1; ++dy) {
        int vy = ((unsigned)(iy + dy) < (unsigned)hs) && ((unsigned)(jy + dy) < (unsigned)hs);
#pragma unroll
        for (int dx = -1; dx <= 1; ++dx) {
            int vi = vy && ((unsigned)(ix + dx) < (unsigned)hs);
            int o = hs * dy + dx;
            int row = vi ? (i + o) : i;
            f32x4 v = ld4u(&Gb[(size_t)row * Ls + jb + o]);
            f32x4 m;
#pragma unroll
            for (int ln = 0; ln < 4; ++ln)
                m[ln] = (vi && ((unsigned)(jx0 + ln + dx) < (unsigned)hs)) ? 1.f : 0.f;
            acc += v * m;
        }
    }
    __builtin_memcpy(&Sb[(size_t)i * Ls + jb], &acc, 16);
    int dd = i - jb;
    if ((unsigned)dd < 4u) RNb[i] = 1.0f / fmaxf(sqrtf(acc[dd]), 1e-4f);
}

// fused fuse2(fuse1) with transposed output, vectorized 4j x 4i per thread.
// S must have >=2KB guard bands on both sides.
__global__ __launch_bounds__(256) void fuse12T_k(const float* __restrict__ S, const float* __restrict__ RN,
                                                 float* __restrict__ ZT, long long zsS, long long zsZT, int z0) {
    const float* Sb = S + (size_t)blockIdx.z * zsS;
    float* ZTb = ZT + (size_t)blockIdx.z * zsZT;
    const float* RNb = RN + (size_t)(z0 + blockIdx.z) * Ls;
    __shared__ float tile[64][65];
    const int i0 = blockIdx.y * 64, j0 = blockIdx.x * 64;
    const int t = threadIdx.x;
    const int jg = t & 15, tit = t >> 4;
    const int jb = j0 + jg * 4;
    const int jy0 = jb / hs, jx0 = jb % hs;

    int ccb[9]; f32x4 m4[9];
#pragma unroll
    for (int d2 = -1; d2 <= 1; ++d2) {
        int cl[4], vb[4];
#pragma unroll
        for (int ln = 0; ln < 4; ++ln) {
            int j2 = (jx0 + ln) * hs + jy0 + d2;
            int vv = ((unsigned)j2 < (unsigned)Ls) ? 1 : 0;
            int c = vv ? ((j2 % hs) * hs + j2 / hs) : 0;
            cl[ln] = c; vb[ln] = vv;
        }
        int base = 0;
#pragma unroll
        for (int ln = 0; ln < 4; ++ln) if (vb[ln]) base = cl[ln] - ln;
#pragma unroll
        for (int d1 = -1; d1 <= 1; ++d1) {
            int idx = (d2 + 1) * 3 + (d1 + 1);
            ccb[idx] = base + d1;
            f32x4 mm;
#pragma unroll
            for (int ln = 0; ln < 4; ++ln) {
                int cc = cl[ln] + d1;
                mm[ln] = (vb[ln] && ((unsigned)cc < (unsigned)Ls)) ? 1.f : 0.f;
            }
            m4[idx] = mm;
        }
    }

    f32x4 acc[4] = {};
#pragma unroll
    for (int kk = 0; kk < 4; ++kk) {
        const int i = i0 + tit * 4 + kk;
        const int iy = i / hs, ix = i % hs;
        const int tif = ix * hs + iy;
#pragma unroll
        for (int d2 = -1; d2 <= 1; ++d2) {
            int i2 = tif + d2;
            int vi = ((unsigned)i2 < (unsigned)Ls) ? 1 : 0;
            int r = vi ? ((i2 % hs) * hs + i2 / hs) : 1;
#pragma unroll
            for (int d1 = -1; d1 <= 1; ++d1) {
                int rr = r + d1;
                int vr = vi && ((unsigned)rr < (unsigned)Ls);
                int rrc = vr ? rr : 0;
                float w = RNb[rrc];
                w = vr ? w : 0.f;
                int idx = (d2 + 1) * 3 + (d1 + 1);
                f32x4 v = ld4u(&Sb[(size_t)rrc * Ls + ccb[idx]]);
                acc[kk] += v * m4[idx] * w;
            }
        }
    }
#pragma unroll
    for (int kk = 0; kk < 4; ++kk) {
        int ti = tit * 4 + kk;
        tile[ti][jg * 4 + 0] = acc[kk][0];
        tile[ti][jg * 4 + 1] = acc[kk][1];
        tile[ti][jg * 4 + 2] = acc[kk][2];
        tile[ti][jg * 4 + 3] = acc[kk][3];
    }
    __syncthreads();
    const int r2 = t >> 2, cs = (t & 3) * 16;
    float vbuf[16];
#pragma unroll
    for (int k = 0; k < 16; ++k) vbuf[k] = tile[cs + k][r2];
    float* dst = &ZTb[(size_t)(j0 + r2) * Ls + i0 + cs];
#pragma unroll
    for (int k = 0; k < 4; ++k)
        *(float4*)&dst[k * 4] = *(float4*)&vbuf[k * 4];
}

// row softmax over ZT[p][l] (coalesced), writes bf16 AT[p][l]
__global__ __launch_bounds__(256) void softmax_row_k(const float* __restrict__ ZT, const float* __restrict__ MM,
                                                     unsigned short* __restrict__ AT, long long zsZT, int z0) {
    const int z = z0 + blockIdx.z;
    const float* ZTb = ZT + (size_t)blockIdx.z * zsZT;
    const float* MMb = MM + (size_t)z * Ls;
    unsigned short* ATb = AT + (size_t)z * Ls * Ls;
    const int w = threadIdx.x >> 6, lane = threadIdx.x & 63;
    const int p = blockIdx.x * 4 + w;
    const float* row = ZTb + (size_t)p * Ls;
    float v[36];
    float mx = -3.4e38f;
#pragma unroll
    for (int k = 0; k < 9; ++k) {
        const float4 zv = *(const float4*)&row[k * 256 + lane * 4];
        const float4 m = *(const float4*)&MMb[k * 256 + lane * 4];
        v[4 * k + 0] = zv.x * m.x * 10.f;
        v[4 * k + 1] = zv.y * m.y * 10.f;
        v[4 * k + 2] = zv.z * m.z * 10.f;
        v[4 * k + 3] = zv.w * m.w * 10.f;
        mx = fmaxf(mx, fmaxf(fmaxf(v[4 * k], v[4 * k + 1]), fmaxf(v[4 * k + 2], v[4 * k + 3])));
    }
#pragma unroll
    for (int off = 32; off; off >>= 1) mx = fmaxf(mx, __shfl_xor(mx, off));
    float sum = 0.f;
#pragma unroll
    for (int kk = 0; kk < 36; ++kk) { v[kk] = expf(v[kk] - mx); sum += v[kk]; }
#pragma unroll
    for (int off = 32; off; off >>= 1) sum += __shfl_xor(sum, off);
    const float rs = 1.0f / sum;
#pragma unroll
    for (int k = 0; k < 9; ++k) {
        const float4 m = *(const float4*)&MMb[k * 256 + lane * 4];
        ushort4 o;
        o.x = f2bf(fmaxf(v[4 * k + 0] * rs * m.x, 1e-8f));
        o.y = f2bf(fmaxf(v[4 * k + 1] * rs * m.y, 1e-8f));
        o.z = f2bf(fmaxf(v[4 * k + 2] * rs * m.z, 1e-8f));
        o.w = f2bf(fmaxf(v[4 * k + 3] * rs * m.w, 1e-8f));
        *(ushort4*)&ATb[(size_t)p * Ls + k * 256 + lane * 4] = o;
    }
}

// raw_w^T gather (bf16, N-major K-contiguous), z-batched
__global__ __launch_bounds__(256) void gather_rwT_k(const float* __restrict__ x1, unsigned short* __restrict__ RWT) {
    const int z = blockIdx.z;
    const float* x1b = x1 + (size_t)z * Cc * Hh * Hh;
    unsigned short* R = RWT + (size_t)z * CK * Ls;
    int l = blockIdx.x * 256 + threadIdx.x;   // < 2304
    int ck = blockIdx.y;                      // < 2048
    int c = ck >> 4, a = (ck >> 2) & 3, b2 = ck & 3;
    int ly = l / hs, lx = l % hs;
    int u = 2 * ly + a - 1, vv = 2 * lx + b2 - 1;
    float val = ((unsigned)u < (unsigned)Hh && (unsigned)vv < (unsigned)Hh) ? x1b[c * (Hh * Hh) + u * Hh + vv] : 0.0f;
    R[(size_t)ck * Ls + l] = f2bf(val);
}

// LDS-gather scatter: block = (channel, yhalf, z); T is bf16.
__global__ __launch_bounds__(256) void scatter3_k(const unsigned short* __restrict__ T, float* __restrict__ out) {
    const int z = blockIdx.z;
    const int c = blockIdx.x;
    const int yh = blockIdx.y;                 // 0 or 1
    const unsigned short* Tb = T + (size_t)z * Ls * CK + (size_t)c * 16;
    float* outb = out + (size_t)z * Cc * Hh * Hh + (size_t)c * Hh * Hh;
    const int i0 = (yh == 0) ? 0 : 23;          // i range [i0, i0+25)
    __shared__ unsigned short Tl[1200 * 16];    // 25*48 rows x 16 bf16 = 38.4 KB
    const int t = threadIdx.x;
#pragma unroll
    for (int rep = 0; rep < 5; ++rep) {
        int p = rep * 256 + t;
        if (p < 1200)
            __builtin_memcpy(&Tl[p * 16], &Tb[(size_t)(i0 * hs + p) * CK], 32);
    }
    __syncthreads();
#pragma unroll
    for (int rep = 0; rep < 5; ++rep) {
        int idx4 = rep * 256 + t;              // < 1152 (48 rows x 24 float4)
        if (idx4 >= 1152) break;
        int Y = yh * 48 + idx4 / 24;
        int X0 = (idx4 % 24) * 4;
        float o4[4];
#pragma unroll
        for (int xi = 0; xi < 4; ++xi) {
            int X = X0 + xi;
            int a0 = (Y + 1) & 1, b0 = (X + 1) & 1;
            float s = 0.f;
#pragma unroll
            for (int ai = 0; ai < 2; ++ai) {
                int a = a0 + 2 * ai;
                int i = (Y + 1 - a) >> 1;
                if ((unsigned)i >= (unsigned)hs) continue;
#pragma unroll
                for (int bi = 0; bi < 2; ++bi) {
                    int b2 = b0 + 2 * bi;
                    int jj = (X + 1 - b2) >> 1;
                    if ((unsigned)jj >= (unsigned)hs) continue;
                    s += bf2f(Tl[((i - i0) * hs + jj) * 16 + a * 4 + b2]);
                }
            }
            o4[xi] = 0.25f * s;
        }
        *(float4*)&outb[Y * Hh + X0] = *(float4*)&o4[0];
    }
}

// ---------------- bf16 MFMA GEMM, 2-phase double-buffered, LDS slot-swizzled ----------------
// C[M,N] = A[M,K] * Bt[N,K]^T, z-batched. SUPER: 4x3 supertile remap (grid must be 16x18).
// CBF16: C written as bf16, else f32.  (round-7/12/14 verified form, BK=32)
template <int SUPER, int CBF16>
__global__ __launch_bounds__(256) void mfma_gemm_k(const unsigned short* __restrict__ A,
                                                   const unsigned short* __restrict__ Bt,
                                                   void* __restrict__ Cv, int M, int N, int K,
                                                   long long sA, long long sB, long long sC) {
    A  += (size_t)blockIdx.z * sA;
    Bt += (size_t)blockIdx.z * sB;
    float* Cf = (float*)Cv + (CBF16 ? 0 : (size_t)blockIdx.z * sC);
    unsigned short* Ch = (unsigned short*)Cv + (CBF16 ? (size_t)blockIdx.z * sC : 0);

    // bijective XCD-aware remap over (x,y)
    const int nb = gridDim.x * gridDim.y;
    const int flat = blockIdx.y * gridDim.x + blockIdx.x;
    const int q = nb >> 3, r = nb & 7;
    const int xcd = flat & 7, sidx = flat >> 3;
    const int wg = (xcd < r ? xcd * (q + 1) : r * (q + 1) + (xcd - r) * q) + sidx;
    int bm, bn;
    if (SUPER) {
        int st = wg / 12, tt = wg % 12;
        int stn = st & 3, stm = st >> 2;     // 4 x 6 supertile grid
        int tn = tt & 3, tm = tt >> 2;       // 4(n) x 3(m) within
        bn = (stn * 4 + tn) * 128;
        bm = (stm * 3 + tm) * 128;
    } else {
        bm = (wg / gridDim.x) * 128;
        bn = (wg % gridDim.x) * 128;
    }

    __shared__ __align__(16) unsigned short Asm[2][128 * 32];
    __shared__ __align__(16) unsigned short Bsm[2][128 * 32];
    const int t = threadIdx.x;
    const int lane = t & 63, w = t >> 6;
    const int wr = w >> 1, wc = w & 1;

    // staging: lane's 16B -> row rA, phys slot (lane&3); logical kslot = (lane&3)^((rA>>1)&3)
    const int rA = 32 * w + (lane >> 2);
    const int kA = (((lane & 3) ^ ((lane >> 3) & 3))) * 8;
    const unsigned short* gA0 = A + (size_t)(bm + rA) * K + kA;
    const unsigned short* gA1 = gA0 + (size_t)16 * K;   // row rA+16: same swizzle
    const unsigned short* gB0 = Bt + (size_t)(bn + rA) * K + kA;
    const unsigned short* gB1 = gB0 + (size_t)16 * K;

#define STAGE4(b, koff) do { \
        GLOAD_LDS16(gA0 + (koff), &Asm[b][(2 * w) * 512]); \
        GLOAD_LDS16(gA1 + (koff), &Asm[b][(2 * w + 1) * 512]); \
        GLOAD_LDS16(gB0 + (koff), &Bsm[b][(2 * w) * 512]); \
        GLOAD_LDS16(gB1 + (koff), &Bsm[b][(2 * w + 1) * 512]); \
    } while (0)

    const int fr = lane & 15, fq = lane >> 4;
    const int sqa = (fq ^ ((fr >> 1) & 3)) * 8;     // read-side swizzle
    f32x4 acc[4][4] = {};

    const int nt = K >> 5;
    STAGE4(0, 0);
    __syncthreads();
    int cur = 0;
    for (int tt = 0; tt < nt; ++tt) {
        if (tt + 1 < nt) STAGE4(cur ^ 1, (tt + 1) * 32);
        short8 av[4], bv[4];
#pragma unroll
        for (int m = 0; m < 4; ++m)
            av[m] = *(const short8*)&Asm[cur][(wr * 64 + m * 16 + fr) * 32 + sqa];
#pragma unroll
        for (int n = 0; n < 4; ++n)
            bv[n] = *(const short8*)&Bsm[cur][(wc * 64 + n * 16 + fr) * 32 + sqa];
#pragma unroll
        for (int m = 0; m < 4; ++m)
#pragma unroll
            for (int n = 0; n < 4; ++n)
                acc[m][n] = __builtin_amdgcn_mfma_f32_16x16x32_bf16(av[m], bv[n], acc[m][n], 0, 0, 0);
        __syncthreads();
        cur ^= 1;
    }
#undef STAGE4

#pragma unroll
    for (int m = 0; m < 4; ++m) {
        int row0 = bm + wr * 64 + m * 16 + fq * 4;
#pragma unroll
        for (int n = 0; n < 4; ++n) {
            int col = bn + wc * 64 + n * 16 + fr;
#pragma unroll
            for (int rr = 0; rr < 4; ++rr) {
                if (CBF16)
                    Ch[(size_t)(row0 + rr) * N + col] = f2bf(acc[m][n][rr]);
                else
                    Cf[(size_t)(row0 + rr) * N + col] = acc[m][n][rr];
            }
        }
    }
}

// ---------------- launch ----------------

extern "C" void kernel_launch(void* const* d_in, const int* in_sizes, int n_in,
                              void* d_out, int out_size, void* d_ws, size_t ws_size,
                              hipStream_t stream) {
    const float* x1 = (const float*)d_in[0];
    const float* x2 = (const float*)d_in[1];
    const float* mask = (const float*)d_in[2];
    float* out = (float*)d_out;

    char* base = (char*)d_ws;
    const size_t LsLs = (size_t)Ls * Ls;
    const size_t LsCK = (size_t)Ls * CK;
    const long long sPQ = (long long)Ls * KG;

    const bool batched = ws_size >= 132175872ull;

    float* MM2 = (float*)(base);
    float* RN2 = (float*)(base + 20480);
    unsigned short *P, *Q, *ATb2, *RWT2;
    float *G, *S;
    unsigned short* T2 = (unsigned short*)base;   // bf16 overlay: 18.9MB (region dead by deconv time)
    if (batched) {
        P    = (unsigned short*)(base + 40960);
        Q    = (unsigned short*)(base + 3584000);
        G    = (float*)(base + 7127040);        // 2KB guards around
        S    = (float*)(base + 49598464);       // 2KB guards around
        ATb2 = (unsigned short*)(base + 92067840);
        RWT2 = (unsigned short*)(base + 113301504);   // end 132,175,872
    } else {
        P    = (unsigned short*)(base + 40960);
        Q    = (unsigned short*)(base + 1812480);
        G    = (float*)(base + 3586048);
        S    = (float*)(base + 24823808);
        ATb2 = (unsigned short*)(base + 46059520);
        RWT2 = (unsigned short*)(base + 67293184);    // end 86,167,552
    }

    mm_k<<<dim3(Ls / 256, 2), 256, 0, stream>>>(mask, MM2);
    gather_rwT_k<<<dim3(Ls / 256, CK, 2), 256, 0, stream>>>(x1, RWT2);

    const int tapsGrid = (Ls * 576) / 256;   // 5184

    if (batched) {
        transposePQ_k<<<dim3(2, Ls / 64, 2), 256, 0, stream>>>(x2, P, Q, sPQ, 0);
        mfma_gemm_k<0, 0><<<dim3(Ls / 128, Ls / 128, 2), 256, 0, stream>>>(
            P, Q, G, Ls, Ls, KG, sPQ, sPQ, (long long)LsLs);
        taps9rn_k<<<dim3(tapsGrid, 1, 2), 256, 0, stream>>>(G, S, RN2, (long long)LsLs, (long long)LsLs, 0);
        fuse12T_k<<<dim3(Ls / 64, Ls / 64, 2), 256, 0, stream>>>(S, RN2, G, (long long)LsLs, (long long)LsLs, 0);
        softmax_row_k<<<dim3(Ls / 4, 1, 2), 256, 0, stream>>>(G, MM2, ATb2, (long long)LsLs, 0);
    } else {
        for (int z0 = 0; z0 < 2; ++z0) {
            transposePQ_k<<<dim3(2, Ls / 64, 1), 256, 0, stream>>>(x2, P, Q, 0, z0);
            mfma_gemm_k<0, 0><<<dim3(Ls / 128, Ls / 128, 1), 256, 0, stream>>>(
                P, Q, G, Ls, Ls, KG, 0, 0, 0);
            taps9rn_k<<<dim3(tapsGrid, 1, 1), 256, 0, stream>>>(G, S, RN2, 0, 0, z0);
            fuse12T_k<<<dim3(Ls / 64, Ls / 64, 1), 256, 0, stream>>>(S, RN2, G, 0, 0, z0);
            softmax_row_k<<<dim3(Ls / 4, 1, 1), 256, 0, stream>>>(G, MM2, ATb2, 0, z0);
        }
    }

    // batched deconv GEMM (bf16 C) with 4x3 supertile swizzle: T = A^T @ RW for both samples
    mfma_gemm_k<1, 1><<<dim3(CK / 128, Ls / 128, 2), 256, 0, stream>>>(
        ATb2, RWT2, T2, Ls, CK, Ls,
        (long long)LsLs, (long long)LsCK, (long long)LsCK);

    scatter3_k<<<dim3(Cc, 2, 2), 256, 0, stream>>>(T2, out);

    (void)in_sizes; (void)n_in; (void)out_size; (void)ws_size;
}